// Round 10
// baseline (271.722 us; speedup 1.0000x reference)
//
#include <hip/hip_runtime.h>
#include <stdint.h>

typedef __bf16 bf16_t;
typedef __bf16 bf16x8 __attribute__((ext_vector_type(8)));
typedef float  f32x4  __attribute__((ext_vector_type(4)));

#define AS1 __attribute__((address_space(1)))
#define AS3 __attribute__((address_space(3)))

__device__ __forceinline__ void gld_lds16(const bf16_t* g, void* s) {
  // async global->LDS, 16 bytes per lane; HW dest = wave-uniform base + lane*16
  __builtin_amdgcn_global_load_lds((const AS1 uint32_t*)g, (AS3 uint32_t*)s, 16, 0, 0);
}

// ---------------------------------------------------------------------------
// 0) fp32 -> bf16 canonicalization, all 4 tensors in ONE dispatch.
// ---------------------------------------------------------------------------
__global__ __launch_bounds__(256) void convert_all_kernel(
    const float* __restrict__ X,  const float* __restrict__ Wq,
    const float* __restrict__ Wk, const float* __restrict__ Wv,
    bf16_t* __restrict__ Xc, bf16_t* __restrict__ Wqc,
    bf16_t* __restrict__ Wkc, bf16_t* __restrict__ Wvc) {
  const int blk = blockIdx.x;
  const float* src; bf16_t* dst; int base;
  if (blk < 4096)      { src = X;  dst = Xc;  base = 0;    }
  else if (blk < 4608) { src = Wq; dst = Wqc; base = 4096; }
  else if (blk < 5120) { src = Wk; dst = Wkc; base = 4608; }
  else                 { src = Wv; dst = Wvc; base = 5120; }
  const int i = ((blk - base) * 256 + threadIdx.x) * 8;
  const float4 a = ((const float4*)(src + i))[0];
  const float4 b = ((const float4*)(src + i))[1];
  bf16x8 v;
  v[0] = (bf16_t)a.x; v[1] = (bf16_t)a.y; v[2] = (bf16_t)a.z; v[3] = (bf16_t)a.w;
  v[4] = (bf16_t)b.x; v[5] = (bf16_t)b.y; v[6] = (bf16_t)b.z; v[7] = (bf16_t)b.w;
  *(bf16x8*)(dst + i) = v;
}

// ---------------------------------------------------------------------------
// 128x128 core (qkv, throughput regime): global_load_lds staging, verified
// 795 TF. XOR-swizzled LDS (conflict-free, verified R4).
// ---------------------------------------------------------------------------
__device__ __forceinline__ void gemm_bt_core(
    const bf16_t* __restrict__ A, int lda,
    const bf16_t* __restrict__ B, int ldb,
    int m0, int n0, int kBeg, int kEnd,
    bf16_t* As, bf16_t* Bs, f32x4 acc[4][4])
{
  const int tid  = threadIdx.x;
  const int lane = tid & 63;
  const int wave = tid >> 6;
  const int wm = (wave >> 1) * 64;
  const int wn = (wave & 1) * 64;
  const int fr = lane & 15;
  const int ck = lane >> 4;

  const int off0 = wave * 2048 + lane * 16;
  const int row0 = wave * 32 + (lane >> 2);
  const int row1 = row0 + 16;
  const int kg   = ((lane & 3) ^ ((row0 >> 1) & 3)) * 8;

  int aoff[4], boff[4];
#pragma unroll
  for (int i = 0; i < 4; ++i) {
    const int ra = wm + i * 16 + fr;
    const int rb = wn + i * 16 + fr;
    aoff[i] = ra * 64 + ((ck ^ ((ra >> 1) & 3)) * 16);
    boff[i] = rb * 64 + ((ck ^ ((rb >> 1) & 3)) * 16);
  }

  for (int kt = kBeg; kt < kEnd; kt += 32) {
    __syncthreads();
    gld_lds16(A + (size_t)(m0 + row0) * lda + kt + kg, (char*)As + off0);
    gld_lds16(A + (size_t)(m0 + row1) * lda + kt + kg, (char*)As + off0 + 1024);
    gld_lds16(B + (size_t)(n0 + row0) * ldb + kt + kg, (char*)Bs + off0);
    gld_lds16(B + (size_t)(n0 + row1) * ldb + kt + kg, (char*)Bs + off0 + 1024);
    __syncthreads();

    bf16x8 af[4], bfv[4];
#pragma unroll
    for (int mi = 0; mi < 4; ++mi)
      af[mi] = *(const bf16x8*)((char*)As + aoff[mi]);
#pragma unroll
    for (int ni = 0; ni < 4; ++ni)
      bfv[ni] = *(const bf16x8*)((char*)Bs + boff[ni]);
#pragma unroll
    for (int mi = 0; mi < 4; ++mi)
#pragma unroll
      for (int ni = 0; ni < 4; ++ni)
        acc[mi][ni] = __builtin_amdgcn_mfma_f32_16x16x32_bf16(
            af[mi], bfv[ni], acc[mi][ni], 0, 0, 0);
  }
}

// ---------------------------------------------------------------------------
// 64x64 PIPELINED core (pv, latency regime): VGPR prefetch of tile k+1
// overlaps compute of tile k. Plain global_load into regs is thread-private,
// so the barrier does NOT vmcnt-drain it (unlike global_load_lds). Barriers
// only protect ds_write->ds_read (cheap lgkm drain). Same swizzled layout:
// thread t covers row t>>2, chunk t&3, LDS byte offset t*16.
// ---------------------------------------------------------------------------
__device__ __forceinline__ void gemm64_pipe(
    const bf16_t* __restrict__ A, int lda,
    const bf16_t* __restrict__ B, int ldb,
    int m0, int n0, int kBeg, int kEnd,
    bf16_t* As, bf16_t* Bs, f32x4 acc[2][2])
{
  const int tid  = threadIdx.x;
  const int lane = tid & 63;
  const int wave = tid >> 6;
  const int wm = (wave >> 1) * 32;
  const int wn = (wave & 1) * 32;
  const int fr = lane & 15;
  const int ck = lane >> 4;

  const int srow = tid >> 2;                         // staging row 0..63
  const int kg   = ((tid & 3) ^ ((srow >> 1) & 3)) * 8;
  const bf16_t* ap = A + (size_t)(m0 + srow) * lda + kg;
  const bf16_t* bp = B + (size_t)(n0 + srow) * ldb + kg;

  int aoff[2], boff[2];
#pragma unroll
  for (int i = 0; i < 2; ++i) {
    const int ra = wm + i * 16 + fr;
    const int rb = wn + i * 16 + fr;
    aoff[i] = ra * 64 + ((ck ^ ((ra >> 1) & 3)) * 16);
    boff[i] = rb * 64 + ((ck ^ ((rb >> 1) & 3)) * 16);
  }

  uint4 pa = *(const uint4*)(ap + kBeg);
  uint4 pb = *(const uint4*)(bp + kBeg);

  for (int kt = kBeg; kt < kEnd; kt += 32) {
    __syncthreads();                              // prev iter's reads done
    *(uint4*)((char*)As + tid * 16) = pa;
    *(uint4*)((char*)Bs + tid * 16) = pb;
    if (kt + 32 < kEnd) {                         // prefetch next (in flight
      pa = *(const uint4*)(ap + kt + 32);         //  across the barrier)
      pb = *(const uint4*)(bp + kt + 32);
    }
    __syncthreads();                              // ds_writes visible

    bf16x8 af[2], bfv[2];
#pragma unroll
    for (int mi = 0; mi < 2; ++mi)
      af[mi] = *(const bf16x8*)((char*)As + aoff[mi]);
#pragma unroll
    for (int ni = 0; ni < 2; ++ni)
      bfv[ni] = *(const bf16x8*)((char*)Bs + boff[ni]);
#pragma unroll
    for (int mi = 0; mi < 2; ++mi)
#pragma unroll
      for (int ni = 0; ni < 2; ++ni)
        acc[mi][ni] = __builtin_amdgcn_mfma_f32_16x16x32_bf16(
            af[mi], bfv[ni], acc[mi][ni], 0, 0, 0);
  }
}

// ---------------------------------------------------------------------------
// 64x128 PIPELINED core (scores): A 4KB (1 chunk/thread), B 8KB (2 chunks).
// Same pipeline as gemm64_pipe.
// ---------------------------------------------------------------------------
__device__ __forceinline__ void gemm64x128_pipe(
    const bf16_t* __restrict__ A, int lda,
    const bf16_t* __restrict__ B, int ldb,
    int m0, int n0, int kEnd,
    bf16_t* As, bf16_t* Bs, f32x4 acc[2][4])
{
  const int tid  = threadIdx.x;
  const int lane = tid & 63;
  const int wave = tid >> 6;
  const int wm = (wave >> 1) * 32;
  const int wn = (wave & 1) * 64;
  const int fr = lane & 15;
  const int ck = lane >> 4;

  const int srow = tid >> 2;
  const int kg   = ((tid & 3) ^ ((srow >> 1) & 3)) * 8;  // (srow+64) same swz
  const bf16_t* ap  = A + (size_t)(m0 + srow) * lda + kg;
  const bf16_t* bp0 = B + (size_t)(n0 + srow) * ldb + kg;
  const bf16_t* bp1 = B + (size_t)(n0 + srow + 64) * ldb + kg;

  int aoff[2], boff[4];
#pragma unroll
  for (int i = 0; i < 2; ++i) {
    const int ra = wm + i * 16 + fr;
    aoff[i] = ra * 64 + ((ck ^ ((ra >> 1) & 3)) * 16);
  }
#pragma unroll
  for (int i = 0; i < 4; ++i) {
    const int rb = wn + i * 16 + fr;
    boff[i] = rb * 64 + ((ck ^ ((rb >> 1) & 3)) * 16);
  }

  uint4 pa = *(const uint4*)(ap);
  uint4 pb0 = *(const uint4*)(bp0);
  uint4 pb1 = *(const uint4*)(bp1);

  for (int kt = 0; kt < kEnd; kt += 32) {
    __syncthreads();
    *(uint4*)((char*)As + tid * 16) = pa;
    *(uint4*)((char*)Bs + tid * 16) = pb0;
    *(uint4*)((char*)Bs + 4096 + tid * 16) = pb1;
    if (kt + 32 < kEnd) {
      pa  = *(const uint4*)(ap + kt + 32);
      pb0 = *(const uint4*)(bp0 + kt + 32);
      pb1 = *(const uint4*)(bp1 + kt + 32);
    }
    __syncthreads();

    bf16x8 af[2], bfv[4];
#pragma unroll
    for (int mi = 0; mi < 2; ++mi)
      af[mi] = *(const bf16x8*)((char*)As + aoff[mi]);
#pragma unroll
    for (int ni = 0; ni < 4; ++ni)
      bfv[ni] = *(const bf16x8*)((char*)Bs + boff[ni]);
#pragma unroll
    for (int mi = 0; mi < 2; ++mi)
#pragma unroll
      for (int ni = 0; ni < 4; ++ni)
        acc[mi][ni] = __builtin_amdgcn_mfma_f32_16x16x32_bf16(
            af[mi], bfv[ni], acc[mi][ni], 0, 0, 0);
  }
}

// ---------------------------------------------------------------------------
// 1) QKV projection: Out[z][8192,1024] = X * W[z]^T (unchanged, 795 TF)
// ---------------------------------------------------------------------------
__global__ __launch_bounds__(256) void qkv_kernel(
    const bf16_t* __restrict__ X,
    const bf16_t* __restrict__ Wq, const bf16_t* __restrict__ Wk,
    const bf16_t* __restrict__ Wv,
    bf16_t* __restrict__ Q, bf16_t* __restrict__ K, bf16_t* __restrict__ V)
{
  __shared__ bf16_t As[128 * 32];
  __shared__ bf16_t Bs[128 * 32];
  const int m0 = blockIdx.x * 128;
  const int n0 = blockIdx.y * 128;
  const int z  = blockIdx.z;
  const bf16_t* W = (z == 0) ? Wq : (z == 1) ? Wk : Wv;
  bf16_t* Out     = (z == 0) ? Q  : (z == 1) ? K  : V;

  f32x4 acc[4][4] = {};
  gemm_bt_core(X, 1024, W, 1024, m0, n0, 0, 1024, As, Bs, acc);

  const int lane = threadIdx.x & 63;
  const int wave = threadIdx.x >> 6;
  const int wm = (wave >> 1) * 64, wn = (wave & 1) * 64;
#pragma unroll
  for (int mi = 0; mi < 4; ++mi)
#pragma unroll
    for (int r = 0; r < 4; ++r) {
      const int row = m0 + wm + mi * 16 + (lane >> 4) * 4 + r;
#pragma unroll
      for (int ni = 0; ni < 4; ++ni) {
        const int col = n0 + wn + ni * 16 + (lane & 15);
        Out[(size_t)row * 1024 + col] = (bf16_t)acc[mi][ni][r];
      }
    }
}

// ---------------------------------------------------------------------------
// 2) V transpose per batch: Vt[b][d][s] = V[b][s][d]
// ---------------------------------------------------------------------------
__global__ __launch_bounds__(256) void vt_kernel(
    const bf16_t* __restrict__ V, bf16_t* __restrict__ Vt)
{
  __shared__ bf16_t t[64][66];
  const int b  = blockIdx.z;
  const int s0 = blockIdx.x * 64;
  const int d0 = blockIdx.y * 64;
  const bf16_t* Vb = V  + (size_t)b * 2048 * 1024;
  bf16_t* Vtb      = Vt + (size_t)b * 1024 * 2048;
  const int c = threadIdx.x & 63, r4 = threadIdx.x >> 6;
#pragma unroll
  for (int i = 0; i < 16; ++i) {
    const int r = r4 + i * 4;
    t[r][c] = Vb[(size_t)(s0 + r) * 1024 + d0 + c];
  }
  __syncthreads();
#pragma unroll
  for (int i = 0; i < 16; ++i) {
    const int r = r4 + i * 4;
    Vtb[(size_t)(d0 + r) * 2048 + s0 + c] = t[c][r];
  }
}

// ---------------------------------------------------------------------------
// 3) Fused scores+exp, 64q x 128k tiles, pipelined core.
// P = exp((Q.K)/32) unnorm bf16 + per-(ktile,row) sums lp.
// ---------------------------------------------------------------------------
__global__ __launch_bounds__(256) void scores_exp_kernel(
    const bf16_t* __restrict__ Q, const bf16_t* __restrict__ K,
    bf16_t* __restrict__ P, float* __restrict__ partials, int b0)
{
  const int kt = blockIdx.x;          // k-tile (128 wide)
  const int m0 = blockIdx.y * 64;     // q (64 rows)
  const int n0 = kt * 128;
  if (n0 > m0 + 63) return;           // fully masked
  __shared__ bf16_t As[64 * 32];
  __shared__ bf16_t Bs[128 * 32];
  __shared__ float rowsum[2][64];
  const int batch = b0 + blockIdx.z;
  const bf16_t* Qb = Q + (size_t)batch * 2048 * 1024;
  const bf16_t* Kb = K + (size_t)batch * 2048 * 1024;
  bf16_t* Pb = P + (size_t)blockIdx.z * 2048 * 2048;
  float* lp  = partials + ((size_t)blockIdx.z * 16 + kt) * 2048;

  f32x4 acc[2][4] = {};
  gemm64x128_pipe(Qb, 1024, Kb, 1024, m0, n0, 1024, As, Bs, acc);

  const int lane = threadIdx.x & 63;
  const int wave = threadIdx.x >> 6;
  const int wm = (wave >> 1) * 32, wn = (wave & 1) * 64;
  const float c = 0.04508422f;        // log2(e)/32
#pragma unroll
  for (int mi = 0; mi < 2; ++mi)
#pragma unroll
    for (int r = 0; r < 4; ++r) {
      const int lrow = wm + mi * 16 + (lane >> 4) * 4 + r;   // 0..63
      const int row  = m0 + lrow;
      float rs = 0.f;
#pragma unroll
      for (int ni = 0; ni < 4; ++ni) {
        const int col = n0 + wn + ni * 16 + (lane & 15);
        float p = exp2f(acc[mi][ni][r] * c);
        if (col > row) p = 0.f;
        const bf16_t pb = (bf16_t)p;
        Pb[(size_t)row * 2048 + col] = pb;
        rs += (float)pb;              // sum the rounded value pv reads
      }
      rs += __shfl_xor(rs, 1);
      rs += __shfl_xor(rs, 2);
      rs += __shfl_xor(rs, 4);
      rs += __shfl_xor(rs, 8);
      if ((lane & 15) == 0) rowsum[wave & 1][lrow] = rs;  // col-half partial
    }
  __syncthreads();
  if (threadIdx.x < 64)
    lp[m0 + threadIdx.x] = rowsum[0][threadIdx.x] + rowsum[1][threadIdx.x];
}

// ---------------------------------------------------------------------------
// 4) PV, 64q x 64d tiles, paired {mt, 31-mt} (uniform 66 k32-iters/block),
// pipelined core. Plain exclusive stores (R7: atomics cost ~40us, banned).
// ---------------------------------------------------------------------------
__global__ __launch_bounds__(256) void pv_kernel(
    const bf16_t* __restrict__ P, const bf16_t* __restrict__ Vt,
    const float* __restrict__ partials, float* __restrict__ out, int b0)
{
  __shared__ bf16_t As[64 * 32];
  __shared__ bf16_t Bs[64 * 32];
  const int n0   = blockIdx.x * 64;         // d
  const int pair = blockIdx.y;              // 0..15
  const int batch = b0 + blockIdx.z;
  const bf16_t* Pb  = P  + (size_t)blockIdx.z * 2048 * 2048;
  const bf16_t* Vtb = Vt + (size_t)batch * 1024 * 2048;
  const float* lp = partials + (size_t)blockIdx.z * 16 * 2048;
  float* ob = out + (size_t)batch * 2048 * 1024;

  const int lane = threadIdx.x & 63;
  const int wave = threadIdx.x >> 6;
  const int wm = (wave >> 1) * 32, wn = (wave & 1) * 32;

#pragma unroll
  for (int t = 0; t < 2; ++t) {
    const int mt = t ? (31 - pair) : pair;  // q64-tile index
    const int m0 = mt * 64;
    const int kEnd = m0 + 64;

    f32x4 acc[2][2] = {};
    gemm64_pipe(Pb, 2048, Vtb, 2048, m0, n0, 0, kEnd, As, Bs, acc);

#pragma unroll
    for (int mi = 0; mi < 2; ++mi)
#pragma unroll
      for (int r = 0; r < 4; ++r) {
        const int row = m0 + wm + mi * 16 + (lane >> 4) * 4 + r;
        const int tmax = row >> 7;          // inclusive 128-k-tile index
        float l = 0.f;
        for (int kt = 0; kt <= tmax; ++kt) l += lp[kt * 2048 + row];
        const float inv = 1.f / l;
#pragma unroll
        for (int ni = 0; ni < 2; ++ni) {
          const int col = n0 + wn + ni * 16 + (lane & 15);
          ob[(size_t)row * 1024 + col] = acc[mi][ni][r] * inv;
        }
      }
  }
}

// ---------------------------------------------------------------------------
extern "C" void kernel_launch(void* const* d_in, const int* in_sizes, int n_in,
                              void* d_out, int out_size, void* d_ws, size_t ws_size,
                              hipStream_t stream) {
  const float* X  = (const float*)d_in[0];
  const float* Wq = (const float*)d_in[1];
  const float* Wk = (const float*)d_in[2];
  const float* Wv = (const float*)d_in[3];
  float* out = (float*)d_out;
  char* ws = (char*)d_ws;

  const size_t NX = (size_t)4 * 2048 * 1024;   // 8.4M elements
  const size_t NW = (size_t)1024 * 1024;       // 1M elements
  const size_t QKV_BYTES = NX * 2;             // 16 MiB

  size_t  off  = 0;
  bf16_t* Xc   = (bf16_t*)(ws + off); off += NX * 2;
  bf16_t* Wqc  = (bf16_t*)(ws + off); off += NW * 2;
  bf16_t* Wkc  = (bf16_t*)(ws + off); off += NW * 2;
  bf16_t* Wvc  = (bf16_t*)(ws + off); off += NW * 2;
  bf16_t* Q    = (bf16_t*)(ws + off); off += QKV_BYTES;
  bf16_t* K    = (bf16_t*)(ws + off); off += QKV_BYTES;
  bf16_t* V    = (bf16_t*)(ws + off); off += QKV_BYTES;
  bf16_t* Vt   = (bf16_t*)(ws + off); off += QKV_BYTES;

  // per-batch: partials 16*2048 fp32 (128 KB) + P bf16 (8 MiB)
  const size_t L_B = (size_t)16 * 2048 * 4;
  const size_t P_B = (size_t)2048 * 2048 * 2;
  const int NB = (ws_size >= off + 4 * (L_B + P_B)) ? 4 : 1;
  float*  Lp = (float*)(ws + off);
  bf16_t* Pb = (bf16_t*)(ws + off + (size_t)NB * L_B);

  convert_all_kernel<<<dim3(5632), 256, 0, stream>>>(X, Wq, Wk, Wv, Xc, Wqc, Wkc, Wvc);
  qkv_kernel<<<dim3(64, 8, 3), 256, 0, stream>>>(Xc, Wqc, Wkc, Wvc, Q, K, V);
  vt_kernel<<<dim3(32, 16, 4), 256, 0, stream>>>(V, Vt);
  for (int b0 = 0; b0 < 4; b0 += NB) {
    scores_exp_kernel<<<dim3(16, 32, NB), 256, 0, stream>>>(Q, K, Pb, Lp, b0);
    pv_kernel<<<dim3(16, 16, NB), 256, 0, stream>>>(Pb, Vt, Lp, out, b0);
  }
}